// Round 8
// baseline (540.321 us; speedup 1.0000x reference)
//
#include <hip/hip_runtime.h>

#define NB 8
#define CCH 256
#define DQK 32
#define NPIX 4096

typedef __attribute__((ext_vector_type(8))) short short8;
typedef __attribute__((ext_vector_type(4))) float f32x4;
typedef __attribute__((ext_vector_type(4))) unsigned int uint4v;
typedef __attribute__((ext_vector_type(4))) unsigned short ushort4v;

static __device__ __forceinline__ unsigned short f2bf(float f) {
  unsigned int u = __builtin_bit_cast(unsigned int, f);
  u += 0x7FFFu + ((u >> 16) & 1u);
  return (unsigned short)(u >> 16);
}
// pack two f32 into one u32 of 2 bf16 (truncation; bias ~0.2% on P, absorbed by threshold)
static __device__ __forceinline__ unsigned int permpack(float lo, float hi) {
  return __builtin_amdgcn_perm(__builtin_bit_cast(unsigned int, hi),
                               __builtin_bit_cast(unsigned int, lo), 0x07060302u);
}

// ---------------- kernel 0: convert W (320x256 fp32, rows Q|K|V) to bf16 ----------------
__global__ __launch_bounds__(256) void wconv_kernel(
    const float* __restrict__ Wq, const float* __restrict__ Wk,
    const float* __restrict__ Wv, unsigned short* __restrict__ Wbf) {
  const int e = (blockIdx.x * 256 + threadIdx.x) * 4;
  const int m = e >> 8, c = e & 255;
  const float* src;
  if (m < 32) src = Wq + (size_t)m * CCH;
  else if (m < 64) src = Wk + (size_t)(m - 32) * CCH;
  else src = Wv + (size_t)(m - 64) * CCH;
  const float4 v = *(const float4*)(src + c);
  ushort4v o;
  o[0] = f2bf(v.x); o[1] = f2bf(v.y); o[2] = f2bf(v.z); o[3] = f2bf(v.w);
  *(ushort4v*)(Wbf + e) = o;
}

// ---------------- kernel 1: transpose x (B,C,N) fp32 -> xT (B,N,C) bf16 ----------------
__global__ __launch_bounds__(256) void xt_kernel(
    const float* __restrict__ x, unsigned short* __restrict__ xT) {
  const int t = threadIdx.x;
  const int b = blockIdx.x & 7;
  const int p = (blockIdx.x >> 3) * 64 + (t & 63);
  const int w = t >> 6;
  const float* xb = x + (size_t)b * CCH * NPIX + p;
  unsigned short* dst = xT + ((size_t)b * NPIX + p) * CCH + 64 * w;
#pragma unroll
  for (int g = 0; g < 8; ++g) {
    short8 o;
#pragma unroll
    for (int j = 0; j < 8; ++j)
      o[j] = (short)f2bf(xb[(size_t)(64 * w + 8 * g + j) * NPIX]);
    *(short8*)(dst + 8 * g) = o;
  }
}

// ---------------- projection: q,k,v = W x + b (bf16 out) ----------------
__global__ __launch_bounds__(256) void proj_kernel(
    const unsigned short* __restrict__ xT, const unsigned short* __restrict__ Wbf,
    const float* __restrict__ bq, const float* __restrict__ bk,
    const float* __restrict__ bv,
    unsigned short* __restrict__ Qb, unsigned short* __restrict__ Kb,
    unsigned short* __restrict__ Vb) {
  const int t = threadIdx.x;
  const int b = blockIdx.x & 7;
  const int i0 = (blockIdx.x >> 3) * 64;
  const int w = t >> 6, l = t & 63;
  const int lc = l & 15, lg = l >> 4;
  const int m0w = 80 * w;
  const unsigned short* xrow = xT + ((size_t)b * NPIX + i0 + lc) * CCH + lg * 8;
  const unsigned short* wrow = Wbf + (size_t)(m0w + lc) * CCH + lg * 8;

  f32x4 acc[5][4];
#pragma unroll
  for (int mt = 0; mt < 5; ++mt)
#pragma unroll
    for (int nt = 0; nt < 4; ++nt) acc[mt][nt] = (f32x4){0.f, 0.f, 0.f, 0.f};

#pragma unroll
  for (int kk = 0; kk < 8; ++kk) {
    short8 af[5];
#pragma unroll
    for (int mt = 0; mt < 5; ++mt)
      af[mt] = *(const short8*)(wrow + (size_t)(mt * 16) * CCH + kk * 32);
    short8 bf[4];
#pragma unroll
    for (int nt = 0; nt < 4; ++nt)
      bf[nt] = *(const short8*)(xrow + (size_t)(nt * 16) * CCH + kk * 32);
#pragma unroll
    for (int nt = 0; nt < 4; ++nt)
#pragma unroll
      for (int mt = 0; mt < 5; ++mt)
        acc[mt][nt] = __builtin_amdgcn_mfma_f32_16x16x32_bf16(af[mt], bf[nt], acc[mt][nt], 0, 0, 0);
  }
#pragma unroll
  for (int mt = 0; mt < 5; ++mt) {
    const int mbase = m0w + mt * 16;
    const int mrow = mbase + 4 * lg;
    if (mbase < 64) {
      const bool isQ = (mbase < 32);
      const float* bias = isQ ? (bq + mrow) : (bk + (mrow - 32));
      unsigned short* dst = isQ ? (Qb + (size_t)b * NPIX * DQK + mrow)
                                : (Kb + (size_t)b * NPIX * DQK + (mrow - 32));
      const float b0 = bias[0], b1 = bias[1], b2 = bias[2], b3 = bias[3];
#pragma unroll
      for (int nt = 0; nt < 4; ++nt) {
        const int i = i0 + nt * 16 + lc;
        ushort4v o;
        o[0] = f2bf(acc[mt][nt][0] + b0);
        o[1] = f2bf(acc[mt][nt][1] + b1);
        o[2] = f2bf(acc[mt][nt][2] + b2);
        o[3] = f2bf(acc[mt][nt][3] + b3);
        *(ushort4v*)(dst + (size_t)i * DQK) = o;
      }
    } else {
      const int vrow = mbase - 64 + 4 * lg;
#pragma unroll
      for (int jj = 0; jj < 4; ++jj) {
        const float bias = bv[vrow + jj];
        unsigned short* vdst = Vb + ((size_t)b * CCH + vrow + jj) * NPIX + i0;
#pragma unroll
        for (int nt = 0; nt < 4; ++nt)
          vdst[nt * 16 + lc] = f2bf(acc[mt][nt][jj] + bias);
      }
    }
  }
}

// ---------------- fused attention v2: fully wave-independent ----------------
// grid 512 x 512thr (8 waves). b=bid&7 (XCD), q0=(bid>>3)*64. Wave w: all 64 q,
// channel slice c0=32w. Swapped QK leaves P in-register; PV uses a permuted
// k-slot mapping (A and B agree) so NO shuffles/LDS/barriers in the K-loop.
// l = per-lane psum + 2 shfl_xor at end. No-max softmax.
__global__ __launch_bounds__(512) void attn_kernel(
    const unsigned short* __restrict__ Qb,
    const unsigned short* __restrict__ Kb,
    const unsigned short* __restrict__ Vb,
    const float* __restrict__ x,
    const float* __restrict__ gammap,
    float* __restrict__ out) {
  __shared__ float tsc[8][64 * 17];  // per-wave epilogue transpose (35 KB)
  const int t = threadIdx.x;
  const int w = t >> 6, l = t & 63;
  const int lc = l & 15, lg = (l >> 4) & 3;
  const int b = blockIdx.x & 7;
  const int q0 = (blockIdx.x >> 3) * 64;
  const int c0 = 32 * w;

  const unsigned short* Kl = Kb + (size_t)b * NPIX * DQK + (size_t)lc * DQK + lg * 8;
  const unsigned short* Ql = Qb + (size_t)b * NPIX * DQK + (size_t)(q0 + lc) * DQK + lg * 8;
  const unsigned short* Vl = Vb + ((size_t)b * CCH + c0 + lc) * NPIX;
  const f32x4 zero4 = {0.f, 0.f, 0.f, 0.f};

  short8 qa[4];
#pragma unroll
  for (int qf = 0; qf < 4; ++qf)
    qa[qf] = *(const short8*)(Ql + (size_t)(qf * 16) * DQK);

  f32x4 acc[4][2];
#pragma unroll
  for (int qf = 0; qf < 4; ++qf)
#pragma unroll
    for (int ct = 0; ct < 2; ++ct) acc[qf][ct] = zero4;
  float psum[4] = {0.f, 0.f, 0.f, 0.f};

  short8 kfA[4], kfB[4];
#pragma unroll
  for (int kt = 0; kt < 4; ++kt)
    kfA[kt] = *(const short8*)(Kl + (size_t)(kt * 16) * DQK);

  // one key-tile step; KF_CUR holds K[t], KF_NXT receives K[t+1]
#define ATTN_STEP(T, KF_CUR, KF_NXT)                                              \
  {                                                                               \
    const int t_ = (T);                                                           \
    const size_t k0 = (size_t)t_ * 64;                                            \
    /* V loads for this tile: permuted k-slot order, 2x8B per fragment */         \
    uint2 vlo[2][2], vhi[2][2];                                                   \
    _Pragma("unroll") for (int ct = 0; ct < 2; ++ct)                              \
      _Pragma("unroll") for (int h = 0; h < 2; ++h) {                             \
        const unsigned short* vb_ = Vl + (size_t)(16 * ct) * NPIX + k0 + 32 * h + 4 * lg; \
        vlo[ct][h] = *(const uint2*)vb_;                                          \
        vhi[ct][h] = *(const uint2*)(vb_ + 16);                                   \
      }                                                                           \
    /* prefetch next K tile */                                                    \
    const size_t kn = (size_t)(t_ < 63 ? t_ + 1 : 63) * 64;                       \
    _Pragma("unroll") for (int kt = 0; kt < 4; ++kt)                              \
      KF_NXT[kt] = *(const short8*)(Kl + (kn + kt * 16) * DQK);                   \
    /* QK + exp + pack (all register-local) */                                    \
    unsigned int pr[4][4][2];                                                     \
    _Pragma("unroll") for (int kt = 0; kt < 4; ++kt) {                            \
      f32x4 s[4];                                                                 \
      _Pragma("unroll") for (int qf = 0; qf < 4; ++qf)                            \
        s[qf] = __builtin_amdgcn_mfma_f32_16x16x32_bf16(KF_CUR[kt], qa[qf], zero4, 0, 0, 0); \
      _Pragma("unroll") for (int qf = 0; qf < 4; ++qf) {                          \
        const float p0 = __expf(s[qf][0]), p1 = __expf(s[qf][1]);                 \
        const float p2 = __expf(s[qf][2]), p3 = __expf(s[qf][3]);                 \
        psum[qf] += (p0 + p1) + (p2 + p3);                                        \
        pr[kt][qf][0] = permpack(p0, p1);                                         \
        pr[kt][qf][1] = permpack(p2, p3);                                         \
      }                                                                           \
    }                                                                             \
    /* PV: A-frag = registers as-is; B-frag loaded in matching permuted order */  \
    _Pragma("unroll") for (int h = 0; h < 2; ++h) {                               \
      short8 pa[4], vf[2];                                                        \
      _Pragma("unroll") for (int qf = 0; qf < 4; ++qf)                            \
        pa[qf] = __builtin_bit_cast(short8, (uint4v){pr[2 * h][qf][0], pr[2 * h][qf][1], \
                                                     pr[2 * h + 1][qf][0], pr[2 * h + 1][qf][1]}); \
      _Pragma("unroll") for (int ct = 0; ct < 2; ++ct)                            \
        vf[ct] = __builtin_bit_cast(short8, (uint4v){vlo[ct][h].x, vlo[ct][h].y,  \
                                                     vhi[ct][h].x, vhi[ct][h].y}); \
      _Pragma("unroll") for (int ct = 0; ct < 2; ++ct)                            \
        _Pragma("unroll") for (int qf = 0; qf < 4; ++qf)                          \
          acc[qf][ct] = __builtin_amdgcn_mfma_f32_16x16x32_bf16(pa[qf], vf[ct], acc[qf][ct], 0, 0, 0); \
    }                                                                             \
  }

  for (int ks = 0; ks < 64; ks += 2) {
    ATTN_STEP(ks, kfA, kfB);
    ATTN_STEP(ks + 1, kfB, kfA);
  }
#undef ATTN_STEP

  // l: reduce psum across the 4 lane-groups -> every lane holds l(q=16qf+lc)
  float lred[4];
#pragma unroll
  for (int qf = 0; qf < 4; ++qf) {
    float v = psum[qf];
    v += __shfl_xor(v, 16);
    v += __shfl_xor(v, 32);
    lred[qf] = v;
  }
  const float g = gammap[0];
  float linv[4][4];  // for acc rows q = 16qf + 4lg + jj
#pragma unroll
  for (int qf = 0; qf < 4; ++qf)
#pragma unroll
    for (int jj = 0; jj < 4; ++jj)
      linv[qf][jj] = g / __shfl(lred[qf], 4 * lg + jj);

  // epilogue: per-wave LDS transpose in two 16-channel chunks, 256B-coalesced stores
  float* tw = tsc[w];
  const float* xbp = x + ((size_t)b * CCH + c0) * NPIX;
  float* ob = out + ((size_t)b * CCH + c0) * NPIX;
#pragma unroll
  for (int ct = 0; ct < 2; ++ct) {
#pragma unroll
    for (int qf = 0; qf < 4; ++qf)
#pragma unroll
      for (int jj = 0; jj < 4; ++jj)
        tw[(16 * qf + 4 * lg + jj) * 17 + lc] = acc[qf][ct][jj] * linv[qf][jj];
    // in-order DS pipe per wave: reads below see the writes above
#pragma unroll
    for (int p2 = 0; p2 < 4; ++p2) {
      const int cl = (l >> 4) + 4 * p2;  // 0..15
      const int qx = 4 * lc;             // 0..60
      float4 o;
      o.x = tw[(qx + 0) * 17 + cl];
      o.y = tw[(qx + 1) * 17 + cl];
      o.z = tw[(qx + 2) * 17 + cl];
      o.w = tw[(qx + 3) * 17 + cl];
      const size_t idx = (size_t)(16 * ct + cl) * NPIX + q0 + qx;
      const float4 xv = *(const float4*)(xbp + idx);
      float4 ov;
      ov.x = o.x + xv.x; ov.y = o.y + xv.y; ov.z = o.z + xv.z; ov.w = o.w + xv.w;
      *(float4*)(ob + idx) = ov;
    }
  }
}

extern "C" void kernel_launch(void* const* d_in, const int* in_sizes, int n_in,
                              void* d_out, int out_size, void* d_ws, size_t ws_size,
                              hipStream_t stream) {
  (void)in_sizes; (void)n_in; (void)out_size; (void)ws_size;
  const float* x     = (const float*)d_in[0];
  const float* Wq    = (const float*)d_in[1];
  const float* bq    = (const float*)d_in[2];
  const float* Wk    = (const float*)d_in[3];
  const float* bk    = (const float*)d_in[4];
  const float* Wv    = (const float*)d_in[5];
  const float* bv    = (const float*)d_in[6];
  const float* gamma = (const float*)d_in[7];

  unsigned short* Wbf = (unsigned short*)d_ws;            // 160 KB
  unsigned short* Qb  = Wbf + 320 * CCH;                  // 2 MB
  unsigned short* Kb  = Qb + (size_t)NB * NPIX * DQK;     // 2 MB
  unsigned short* Vb  = Kb + (size_t)NB * NPIX * DQK;     // 16 MB
  // xT (16 MB bf16) lives in d_out: consumed by proj, overwritten by attn epilogue.
  unsigned short* xT  = (unsigned short*)d_out;

  wconv_kernel<<<80, 256, 0, stream>>>(Wq, Wk, Wv, Wbf);
  xt_kernel<<<512, 256, 0, stream>>>(x, xT);
  proj_kernel<<<512, 256, 0, stream>>>(xT, Wbf, bq, bk, bv, Qb, Kb, Vb);
  attn_kernel<<<512, 512, 0, stream>>>(Qb, Kb, Vb, x, gamma, (float*)d_out);
}

// Round 9
// 331.988 us; speedup vs baseline: 1.6275x; 1.6275x over previous
//
#include <hip/hip_runtime.h>

#define NB 8
#define CCH 256
#define DQK 32
#define NPIX 4096

typedef __attribute__((ext_vector_type(8))) short short8;
typedef __attribute__((ext_vector_type(4))) float f32x4;
typedef __attribute__((ext_vector_type(4))) unsigned int uint4v;
typedef __attribute__((ext_vector_type(4))) unsigned short ushort4v;

static __device__ __forceinline__ unsigned short f2bf(float f) {
  unsigned int u = __builtin_bit_cast(unsigned int, f);
  u += 0x7FFFu + ((u >> 16) & 1u);
  return (unsigned short)(u >> 16);
}
// pack two f32 into one u32 of 2 bf16 (truncation)
static __device__ __forceinline__ unsigned int permpack(float lo, float hi) {
  return __builtin_amdgcn_perm(__builtin_bit_cast(unsigned int, hi),
                               __builtin_bit_cast(unsigned int, lo), 0x07060302u);
}

// ---------------- kernel 0: convert W (320x256 fp32, rows Q|K|V) to bf16 ----------------
__global__ __launch_bounds__(256) void wconv_kernel(
    const float* __restrict__ Wq, const float* __restrict__ Wk,
    const float* __restrict__ Wv, unsigned short* __restrict__ Wbf) {
  const int e = (blockIdx.x * 256 + threadIdx.x) * 4;
  const int m = e >> 8, c = e & 255;
  const float* src;
  if (m < 32) src = Wq + (size_t)m * CCH;
  else if (m < 64) src = Wk + (size_t)(m - 32) * CCH;
  else src = Wv + (size_t)(m - 64) * CCH;
  const float4 v = *(const float4*)(src + c);
  ushort4v o;
  o[0] = f2bf(v.x); o[1] = f2bf(v.y); o[2] = f2bf(v.z); o[3] = f2bf(v.w);
  *(ushort4v*)(Wbf + e) = o;
}

// ---------------- kernel 1: transpose x (B,C,N) fp32 -> xT (B,N,C) bf16 ----------------
__global__ __launch_bounds__(256) void xt_kernel(
    const float* __restrict__ x, unsigned short* __restrict__ xT) {
  const int t = threadIdx.x;
  const int b = blockIdx.x & 7;
  const int p = (blockIdx.x >> 3) * 64 + (t & 63);
  const int w = t >> 6;
  const float* xb = x + (size_t)b * CCH * NPIX + p;
  unsigned short* dst = xT + ((size_t)b * NPIX + p) * CCH + 64 * w;
#pragma unroll
  for (int g = 0; g < 8; ++g) {
    short8 o;
#pragma unroll
    for (int j = 0; j < 8; ++j)
      o[j] = (short)f2bf(xb[(size_t)(64 * w + 8 * g + j) * NPIX]);
    *(short8*)(dst + 8 * g) = o;
  }
}

// ---------------- projection: q,k,v = W x + b (bf16 out) ----------------
__global__ __launch_bounds__(256) void proj_kernel(
    const unsigned short* __restrict__ xT, const unsigned short* __restrict__ Wbf,
    const float* __restrict__ bq, const float* __restrict__ bk,
    const float* __restrict__ bv,
    unsigned short* __restrict__ Qb, unsigned short* __restrict__ Kb,
    unsigned short* __restrict__ Vb) {
  const int t = threadIdx.x;
  const int b = blockIdx.x & 7;
  const int i0 = (blockIdx.x >> 3) * 64;
  const int w = t >> 6, l = t & 63;
  const int lc = l & 15, lg = l >> 4;
  const int m0w = 80 * w;
  const unsigned short* xrow = xT + ((size_t)b * NPIX + i0 + lc) * CCH + lg * 8;
  const unsigned short* wrow = Wbf + (size_t)(m0w + lc) * CCH + lg * 8;

  f32x4 acc[5][4];
#pragma unroll
  for (int mt = 0; mt < 5; ++mt)
#pragma unroll
    for (int nt = 0; nt < 4; ++nt) acc[mt][nt] = (f32x4){0.f, 0.f, 0.f, 0.f};

#pragma unroll
  for (int kk = 0; kk < 8; ++kk) {
    short8 af[5];
#pragma unroll
    for (int mt = 0; mt < 5; ++mt)
      af[mt] = *(const short8*)(wrow + (size_t)(mt * 16) * CCH + kk * 32);
    short8 bf[4];
#pragma unroll
    for (int nt = 0; nt < 4; ++nt)
      bf[nt] = *(const short8*)(xrow + (size_t)(nt * 16) * CCH + kk * 32);
#pragma unroll
    for (int nt = 0; nt < 4; ++nt)
#pragma unroll
      for (int mt = 0; mt < 5; ++mt)
        acc[mt][nt] = __builtin_amdgcn_mfma_f32_16x16x32_bf16(af[mt], bf[nt], acc[mt][nt], 0, 0, 0);
  }
#pragma unroll
  for (int mt = 0; mt < 5; ++mt) {
    const int mbase = m0w + mt * 16;
    const int mrow = mbase + 4 * lg;
    if (mbase < 64) {
      const bool isQ = (mbase < 32);
      const float* bias = isQ ? (bq + mrow) : (bk + (mrow - 32));
      unsigned short* dst = isQ ? (Qb + (size_t)b * NPIX * DQK + mrow)
                                : (Kb + (size_t)b * NPIX * DQK + (mrow - 32));
      const float b0 = bias[0], b1 = bias[1], b2 = bias[2], b3 = bias[3];
#pragma unroll
      for (int nt = 0; nt < 4; ++nt) {
        const int i = i0 + nt * 16 + lc;
        ushort4v o;
        o[0] = f2bf(acc[mt][nt][0] + b0);
        o[1] = f2bf(acc[mt][nt][1] + b1);
        o[2] = f2bf(acc[mt][nt][2] + b2);
        o[3] = f2bf(acc[mt][nt][3] + b3);
        *(ushort4v*)(dst + (size_t)i * DQK) = o;
      }
    } else {
      const int vrow = mbase - 64 + 4 * lg;
#pragma unroll
      for (int jj = 0; jj < 4; ++jj) {
        const float bias = bv[vrow + jj];
        unsigned short* vdst = Vb + ((size_t)b * CCH + vrow + jj) * NPIX + i0;
#pragma unroll
        for (int nt = 0; nt < 4; ++nt)
          vdst[nt * 16 + lc] = f2bf(acc[mt][nt][jj] + bias);
      }
    }
  }
}

// ---------------- fused attention v3: 8-wave split-duty, no redundancy ----------------
// grid 512 = b(8, XCD-aligned) x q-tile(64q). Block 512 thr = 8 waves.
// QK duty: wave w -> key-frag ktw=w&3, q-half qh=w>>2: 2 MFMAs + 8 exp/lane.
// PV duty: wave w -> 32-ch slice c0=32w: 16 MFMAs, V direct-global (ch-partitioned).
// P shared via XOR-swizzled double-buffered LDS; ONE raw lgkm barrier per tile.
// l: per-lane psum, cross-wave reduce via tiny lpart LDS table at end. No-max softmax.
union AttnSmem {
  unsigned short p[2][64 * 64];  // 16 KB P double-buffer
  float tsc[8][16 * 68];         // 34.8 KB epilogue transpose (aliases dead P)
};

__global__ __launch_bounds__(512, 4) void attn_kernel(
    const unsigned short* __restrict__ Qb,
    const unsigned short* __restrict__ Kb,
    const unsigned short* __restrict__ Vb,
    const float* __restrict__ x,
    const float* __restrict__ gammap,
    float* __restrict__ out) {
  __shared__ AttnSmem sm;
  __shared__ float lpart[64 * 4];  // [q_local][kt]
  const int t = threadIdx.x;
  const int w = t >> 6, l = t & 63;
  const int lc = l & 15, lg = l >> 4;  // lg in 0..3
  const int ktw = w & 3, qh = w >> 2;
  const int b = blockIdx.x & 7;
  const int q0 = (blockIdx.x >> 3) * 64;
  const int c0 = 32 * w;
  const int psw = (lc & 7) << 3;  // element-index XOR mask

  const unsigned short* Kl = Kb + (size_t)b * NPIX * DQK + (size_t)(16 * ktw + lc) * DQK + lg * 8;
  const unsigned short* Ql = Qb + (size_t)b * NPIX * DQK + (size_t)(q0 + 32 * qh + lc) * DQK + lg * 8;
  const unsigned short* Vl = Vb + ((size_t)b * CCH + c0 + lc) * NPIX + lg * 8;
  const f32x4 zero4 = {0.f, 0.f, 0.f, 0.f};

  short8 qa[2];
#pragma unroll
  for (int f = 0; f < 2; ++f)
    qa[f] = *(const short8*)(Ql + (size_t)(16 * f) * DQK);

  f32x4 acc[4][2];  // O[q=16qf+4lg+jj][ch=c0+16cf+lc]
#pragma unroll
  for (int qf = 0; qf < 4; ++qf)
#pragma unroll
    for (int cf = 0; cf < 2; ++cf) acc[qf][cf] = zero4;
  float psum[2] = {0.f, 0.f};

  short8 vfA[4], vfB[4], kfA, kfB;
  kfA = *(const short8*)Kl;  // K[0] frag (this wave's ktw)

  // prologue: S/P tile 0 -> buf 0
#pragma unroll
  for (int f = 0; f < 2; ++f) {
    const f32x4 s = __builtin_amdgcn_mfma_f32_16x16x32_bf16(kfA, qa[f], zero4, 0, 0, 0);
    const float p0 = __expf(s[0]), p1 = __expf(s[1]);
    const float p2 = __expf(s[2]), p3 = __expf(s[3]);
    psum[f] += (p0 + p1) + (p2 + p3);
    uint2 wv; wv.x = permpack(p0, p1); wv.y = permpack(p2, p3);
    *(uint2*)((char*)sm.p[0] + (32 * qh + 16 * f + lc) * 128 +
              (((16 * ktw + 4 * lg) ^ psw) << 1)) = wv;
  }
#pragma unroll
  for (int ks = 0; ks < 2; ++ks)
#pragma unroll
    for (int cf = 0; cf < 2; ++cf)
      vfA[ks * 2 + cf] = *(const short8*)(Vl + (size_t)(16 * cf) * NPIX + 32 * ks);
  kfB = *(const short8*)(Kl + (size_t)64 * DQK);  // K[1]
  __syncthreads();

#define ATTN_ITER(T, BUF, VF, KF_CUR, VF_NXT, KF_NXT)                               \
  {                                                                                 \
    const int t_ = (T);                                                             \
    if (t_ < 63) { /* prefetch V[t+1]; K[t+2] */                                    \
      const size_t kb2 = (size_t)(t_ + 1) * 64;                                     \
      _Pragma("unroll") for (int ks = 0; ks < 2; ++ks)                              \
        _Pragma("unroll") for (int cf = 0; cf < 2; ++cf)                            \
          VF_NXT[ks * 2 + cf] =                                                     \
              *(const short8*)(Vl + (size_t)(16 * cf) * NPIX + kb2 + 32 * ks);      \
      if (t_ < 62)                                                                  \
        KF_NXT = *(const short8*)(Kl + (size_t)(t_ + 2) * 64 * DQK);                \
    }                                                                               \
    f32x4 s_[2];                                                                    \
    if (t_ < 63) { /* QK for tile t+1 (2 MFMAs, this wave's duty) */                \
      _Pragma("unroll") for (int f = 0; f < 2; ++f)                                 \
        s_[f] = __builtin_amdgcn_mfma_f32_16x16x32_bf16(KF_CUR, qa[f], zero4, 0, 0, 0); \
    }                                                                               \
    const char* pb_ = (const char*)sm.p[BUF];                                       \
    char* pb2_ = (char*)sm.p[(BUF) ^ 1];                                            \
    _Pragma("unroll") for (int ks = 0; ks < 2; ++ks) {                              \
      short8 pa[4];                                                                 \
      _Pragma("unroll") for (int qf = 0; qf < 4; ++qf)                              \
        pa[qf] = *(const short8*)(pb_ + (16 * qf + lc) * 128 +                      \
                                  (((32 * ks + 8 * lg) ^ psw) << 1));               \
      _Pragma("unroll") for (int cf = 0; cf < 2; ++cf)                              \
        _Pragma("unroll") for (int qf = 0; qf < 4; ++qf)                            \
          acc[qf][cf] = __builtin_amdgcn_mfma_f32_16x16x32_bf16(                    \
              pa[qf], VF[ks * 2 + cf], acc[qf][cf], 0, 0, 0);                       \
    }                                                                               \
    if (t_ < 63) { /* exp + pack + publish P[t+1] */                                \
      _Pragma("unroll") for (int f = 0; f < 2; ++f) {                               \
        const float p0 = __expf(s_[f][0]), p1 = __expf(s_[f][1]);                   \
        const float p2 = __expf(s_[f][2]), p3 = __expf(s_[f][3]);                   \
        psum[f] += (p0 + p1) + (p2 + p3);                                           \
        uint2 wv; wv.x = permpack(p0, p1); wv.y = permpack(p2, p3);                 \
        *(uint2*)(pb2_ + (32 * qh + 16 * f + lc) * 128 +                            \
                  (((16 * ktw + 4 * lg) ^ psw) << 1)) = wv;                         \
      }                                                                             \
    }                                                                               \
    asm volatile("s_waitcnt lgkmcnt(0)\n\ts_barrier" ::: "memory");                 \
  }

  for (int ks = 0; ks < 64; ks += 2) {
    ATTN_ITER(ks, 0, vfA, kfB, vfB, kfA);
    ATTN_ITER(ks + 1, 1, vfB, kfA, vfA, kfB);
  }
#undef ATTN_ITER

  // l: reduce psum over lg (16-key groups) then publish per-kt partials
#pragma unroll
  for (int f = 0; f < 2; ++f) {
    float v = psum[f];
    v += __shfl_xor(v, 16);
    v += __shfl_xor(v, 32);
    if (l < 16) lpart[(32 * qh + 16 * f + lc) * 4 + ktw] = v;
  }
  __syncthreads();

  const float g = gammap[0];
  float linv[4][4];
#pragma unroll
  for (int qf = 0; qf < 4; ++qf)
#pragma unroll
    for (int jj = 0; jj < 4; ++jj) {
      const f32x4 lp = *(const f32x4*)&lpart[(16 * qf + 4 * lg + jj) * 4];
      linv[qf][jj] = g / ((lp[0] + lp[1]) + (lp[2] + lp[3]));
    }

  // epilogue: per-wave LDS transpose (aliases dead P buffers; all P reads drained)
  float* tw = sm.tsc[w];
  const float* xbp = x + ((size_t)b * CCH + c0) * NPIX;
  float* ob = out + ((size_t)b * CCH + c0) * NPIX;
#pragma unroll
  for (int cf = 0; cf < 2; ++cf) {
#pragma unroll
    for (int qf = 0; qf < 4; ++qf) {
      f32x4 o;
#pragma unroll
      for (int jj = 0; jj < 4; ++jj) o[jj] = acc[qf][cf][jj] * linv[qf][jj];
      *(f32x4*)(tw + lc * 68 + 16 * qf + 4 * lg) = o;  // [ch-local=lc][q]
    }
    // per-wave in-order DS pipe handles RAW/WAR
#pragma unroll
    for (int p2 = 0; p2 < 4; ++p2) {
      const int cl = lg + 4 * p2;  // 0..15
      const int qx = 4 * lc;       // 0..60
      const f32x4 o = *(const f32x4*)(tw + cl * 68 + qx);
      const size_t idx = (size_t)(16 * cf + cl) * NPIX + q0 + qx;
      const float4 xv = *(const float4*)(xbp + idx);
      float4 ov;
      ov.x = o[0] + xv.x; ov.y = o[1] + xv.y; ov.z = o[2] + xv.z; ov.w = o[3] + xv.w;
      *(float4*)(ob + idx) = ov;
    }
  }
}

extern "C" void kernel_launch(void* const* d_in, const int* in_sizes, int n_in,
                              void* d_out, int out_size, void* d_ws, size_t ws_size,
                              hipStream_t stream) {
  (void)in_sizes; (void)n_in; (void)out_size; (void)ws_size;
  const float* x     = (const float*)d_in[0];
  const float* Wq    = (const float*)d_in[1];
  const float* bq    = (const float*)d_in[2];
  const float* Wk    = (const float*)d_in[3];
  const float* bk    = (const float*)d_in[4];
  const float* Wv    = (const float*)d_in[5];
  const float* bv    = (const float*)d_in[6];
  const float* gamma = (const float*)d_in[7];

  unsigned short* Wbf = (unsigned short*)d_ws;            // 160 KB
  unsigned short* Qb  = Wbf + 320 * CCH;                  // 2 MB
  unsigned short* Kb  = Qb + (size_t)NB * NPIX * DQK;     // 2 MB
  unsigned short* Vb  = Kb + (size_t)NB * NPIX * DQK;     // 16 MB
  // xT (16 MB bf16) lives in d_out: consumed by proj, overwritten by attn epilogue.
  unsigned short* xT  = (unsigned short*)d_out;

  wconv_kernel<<<80, 256, 0, stream>>>(Wq, Wk, Wv, Wbf);
  xt_kernel<<<512, 256, 0, stream>>>(x, xT);
  proj_kernel<<<512, 256, 0, stream>>>(xT, Wbf, bq, bk, bv, Qb, Kb, Vb);
  attn_kernel<<<512, 512, 0, stream>>>(Qb, Kb, Vb, x, gamma, (float*)d_out);
}